// Round 10
// baseline (202.646 us; speedup 1.0000x reference)
//
#include <hip/hip_runtime.h>
#include <hip/hip_bf16.h>

#define B_ 16
#define N_ 1024
#define F_ 256
#define ALPHA 0.2f
#define NEG_BIG -9.0e15f
#define LOG2E 1.4426950408889634f

typedef float f4 __attribute__((ext_vector_type(4)));
typedef float f32x4 __attribute__((ext_vector_type(4)));
typedef short s16x8 __attribute__((ext_vector_type(8)));
typedef short s16x4 __attribute__((ext_vector_type(4)));

__device__ inline short f2bs(float x) {
    __hip_bfloat16 h = __float2bfloat16(x);
    return __builtin_bit_cast(short, h);
}

// ---------------------------------------------------------------------------
// K_pre: role A (blocks 0..63): wa = [W@a1 ; W@a2]; role B (64..79): WTb[f][k]
// = bf16(W^T) via LDS transpose.
// ---------------------------------------------------------------------------
__global__ __launch_bounds__(256) void k_pre(const float* __restrict__ W,
                                             const float* __restrict__ a,
                                             float* __restrict__ wa,
                                             unsigned short* __restrict__ WTb) {
    const int t = threadIdx.x, lane = t & 63, w = t >> 6;
    if (blockIdx.x < 64) {
        const int row = blockIdx.x * 4 + w;
        const f4 wv = *(const f4*)(W + (size_t)row * F_ + lane * 4);
        const f4 a1 = *(const f4*)(a + lane * 4);
        const f4 a2 = *(const f4*)(a + F_ + lane * 4);
        float s1 = wv[0]*a1[0] + wv[1]*a1[1] + wv[2]*a1[2] + wv[3]*a1[3];
        float s2 = wv[0]*a2[0] + wv[1]*a2[1] + wv[2]*a2[2] + wv[3]*a2[3];
#pragma unroll
        for (int off = 32; off > 0; off >>= 1) {
            s1 += __shfl_xor(s1, off);
            s2 += __shfl_xor(s2, off);
        }
        if (lane == 0) { wa[row] = s1; wa[256 + row] = s2; }
    } else {
        __shared__ float tile[64][65];
        const int wb = blockIdx.x - 64;
        const int k0 = (wb >> 2) * 64, f0 = (wb & 3) * 64;
#pragma unroll
        for (int rep = 0; rep < 4; ++rep) {
            const int idx = rep * 256 + t;
            const int kr = idx >> 4, fc = (idx & 15) * 4;
            const f4 v = *(const f4*)(W + (size_t)(k0 + kr) * F_ + f0 + fc);
            tile[kr][fc] = v[0]; tile[kr][fc + 1] = v[1];
            tile[kr][fc + 2] = v[2]; tile[kr][fc + 3] = v[3];
        }
        __syncthreads();
#pragma unroll
        for (int rep = 0; rep < 4; ++rep) {
            const int idx = rep * 256 + t;
            const int fr = idx >> 4, kc = (idx & 15) * 4;
            s16x4 v;
            v[0] = f2bs(tile[kc][fr]);     v[1] = f2bs(tile[kc + 1][fr]);
            v[2] = f2bs(tile[kc + 2][fr]); v[3] = f2bs(tile[kc + 3][fr]);
            *(s16x4*)(WTb + (size_t)(f0 + fr) * F_ + k0 + kc) = v;
        }
    }
}

// ---------------------------------------------------------------------------
// K_big: three roles by block range:
//  A (0..2047):    adj (64 MB) -> 1-bit mask (2 MB) via __ballot.
//  B (2048..2559): Wh^T GEMM (LDS-free MFMA, WTb L2-resident).
//  C (2560..6655): ei/ej = (h@wa)*log2e.
// ---------------------------------------------------------------------------
__global__ __launch_bounds__(256, 4) void k_big(const float* __restrict__ h,
                                                const unsigned short* __restrict__ WTb,
                                                const float* __restrict__ wa,
                                                const int* __restrict__ adj,
                                                unsigned short* __restrict__ WhT,
                                                float* __restrict__ ei,
                                                float* __restrict__ ej,
                                                unsigned long long* __restrict__ mask) {
    const int bid = blockIdx.x;
    const int t = threadIdx.x, l = t & 63, w = t >> 6;
    if (bid < 2048) {                                     // ---- mask role
        const int gw = bid * 4 + w;
#pragma unroll
        for (int rr = 0; rr < 2; ++rr) {
            const int row = gw + rr * 8192;
            const int* ar = adj + (size_t)row * 1024;
            int v[16];
#pragma unroll
            for (int g = 0; g < 16; ++g) v[g] = ar[g * 64 + l];
            unsigned long long myw = 0;
#pragma unroll
            for (int g = 0; g < 16; ++g) {
                const unsigned long long bal = __ballot(v[g] > 0);
                if (l == g) myw = bal;
            }
            if (l < 16) mask[(size_t)row * 16 + l] = myw;
        }
    } else if (bid < 2560) {                              // ---- gemm role
        const int m0 = (bid - 2048) * 32;
        const int ih = w >> 1, fh = w & 1;
        const int li = l & 15, jg = l >> 4;
        const int mrow = m0 + ih * 16 + li;
        const float* hrow = h + (size_t)mrow * F_ + jg * 8;
        const unsigned short* bbase = WTb + (size_t)(fh * 128 + li) * F_ + jg * 8;
        f32x4 acc[8] = {};
#pragma unroll
        for (int kk = 0; kk < 8; ++kk) {
            const f4 lo = *(const f4*)(hrow + kk * 32);
            const f4 hi = *(const f4*)(hrow + kk * 32 + 4);
            s16x8 av;
            av[0]=f2bs(lo[0]); av[1]=f2bs(lo[1]); av[2]=f2bs(lo[2]); av[3]=f2bs(lo[3]);
            av[4]=f2bs(hi[0]); av[5]=f2bs(hi[1]); av[6]=f2bs(hi[2]); av[7]=f2bs(hi[3]);
#pragma unroll
            for (int ft = 0; ft < 8; ++ft) {
                const s16x8 bv = *(const s16x8*)(bbase + (size_t)ft * 16 * F_ + kk * 32);
                acc[ft] = __builtin_amdgcn_mfma_f32_16x16x32_bf16(av, bv, acc[ft], 0, 0, 0);
            }
        }
        const int bb = m0 >> 10;
        const int mb = (m0 & 1023) + ih * 16 + jg * 4;
#pragma unroll
        for (int ft = 0; ft < 8; ++ft) {
            const int fg = fh * 128 + ft * 16 + li;
            s16x4 v;
            v[0]=f2bs(acc[ft][0]); v[1]=f2bs(acc[ft][1]);
            v[2]=f2bs(acc[ft][2]); v[3]=f2bs(acc[ft][3]);
            *(s16x4*)(WhT + ((size_t)(bb * 256 + fg)) * 1024 + mb) = v;
        }
    } else {                                              // ---- e-vector role
        const int row = (bid - 2560) * 4 + w;
        const f4 hv = *(const f4*)(h + (size_t)row * F_ + l * 4);
        const f4 w1 = *(const f4*)(wa + l * 4);
        const f4 w2 = *(const f4*)(wa + 256 + l * 4);
        float s1 = hv[0]*w1[0] + hv[1]*w1[1] + hv[2]*w1[2] + hv[3]*w1[3];
        float s2 = hv[0]*w2[0] + hv[1]*w2[1] + hv[2]*w2[2] + hv[3]*w2[3];
#pragma unroll
        for (int off = 32; off > 0; off >>= 1) {
            s1 += __shfl_xor(s1, off);
            s2 += __shfl_xor(s2, off);
        }
        if (l == 0) { ei[row] = s1 * LOG2E; ej[row] = s2 * LOG2E; }
    }
}

// ---------------------------------------------------------------------------
// K_attn v3: cooperative softmax, shared-P MFMA. Grid 1024 (16 b x 64 tiles
// of 16 i-rows), 4 blocks/CU. Wave w OWNS rows w*4..w*4+3: computes their
// online softmax ONCE (16-lane shfl reduce), publishes bf16 P[16][72] (pad
// 72 -> A-frag ds_read_b128 at HW-minimum bank occupancy) + rescale sF[16];
// after barrier all 4 waves MFMA their own 64-f slice. B-frags/mask/ej
// prefetched at iter top to hide L2 latency under owner phase. Softmax is
// exact: unmasked running max (constant cancels in p/l ratio), mask applied
// after exp as 0/1 multiply.
// ---------------------------------------------------------------------------
__global__ __launch_bounds__(256, 4) void k_attn(const unsigned short* __restrict__ WhT,
                                                 const float* __restrict__ ei_g,
                                                 const float* __restrict__ ej_g,
                                                 const unsigned long long* __restrict__ mask,
                                                 float* __restrict__ out) {
    const int id = blockIdx.x;
    const int xcd = id & 7, slot = id >> 3;               // 2 batches per XCD
    const int b = xcd * 2 + (slot >> 6);
    const int i0 = (slot & 63) * 16;

    __shared__ unsigned short P_lds[16][72];
    __shared__ __align__(16) float sF[16];

    const int t = threadIdx.x, l = t & 63, w = t >> 6;
    const int li = l & 15, jg = l >> 4;
    const int fbase = w * 64;

    // owner mapping: tile-row = w*4 + jg; 16 lanes (li) cover 64 j, 4 each
    const int orow = w * 4 + jg;
    const float eival = ei_g[b * N_ + i0 + orow];
    const unsigned long long* mrow = mask + (size_t)(b * N_ + i0 + orow) * 16;
    const float* ejb = ej_g + b * N_;

    const unsigned short* whb = WhT + (size_t)b * F_ * N_;
    const unsigned short* bptr[4];
#pragma unroll
    for (int ft = 0; ft < 4; ++ft)
        bptr[ft] = whb + (size_t)(fbase + ft * 16 + li) * N_ + jg * 8;

    float m = NEG_BIG, ll = 0.f;
    f32x4 acc[4] = {};

    for (int s = 0; s < 16; ++s) {
        // ---- prefetch (registers): B-frags, mask word, ej slice
        s16x8 bv0[4], bv1[4];
#pragma unroll
        for (int ft = 0; ft < 4; ++ft) {
            bv0[ft] = *(const s16x8*)(bptr[ft] + s * 64);
            bv1[ft] = *(const s16x8*)(bptr[ft] + s * 64 + 32);
        }
        const unsigned long long w0 = mrow[s];
        const f4 ejv = *(const f4*)(ejb + s * 64 + li * 4);

        // ---- owner phase: softmax for own 4 rows (once per block)
        float p[4];
        float tm = NEG_BIG;
#pragma unroll
        for (int e = 0; e < 4; ++e) {
            float sc = eival + ejv[e];
            sc = fmaxf(sc, ALPHA * sc);                    // leaky
            p[e] = sc;
            tm = fmaxf(tm, sc);
        }
        tm = fmaxf(tm, __shfl_xor(tm, 1));
        tm = fmaxf(tm, __shfl_xor(tm, 2));
        tm = fmaxf(tm, __shfl_xor(tm, 4));
        tm = fmaxf(tm, __shfl_xor(tm, 8));
        const float mn = fmaxf(m, tm);
        const float fac = __builtin_amdgcn_exp2f(m - mn);
        m = mn;
        const unsigned int bits = (unsigned int)(w0 >> (li * 4)) & 0xFu;
        float sum = 0.f;
        s16x4 pw;
#pragma unroll
        for (int e = 0; e < 4; ++e) {
            const float pe = __builtin_amdgcn_exp2f(p[e] - m) *
                             (float)((bits >> e) & 1u);
            pw[e] = f2bs(pe);
            sum += pe;
        }
        sum += __shfl_xor(sum, 1);
        sum += __shfl_xor(sum, 2);
        sum += __shfl_xor(sum, 4);
        sum += __shfl_xor(sum, 8);
        ll = ll * fac + sum;
        if (li == 0) sF[orow] = fac;
        *(s16x4*)&P_lds[orow][li * 4] = pw;
        __syncthreads();

        // ---- consumer phase: rescale + MFMA own f-slice with shared P
        const f4 frv = *(const f4*)&sF[jg * 4];
        const s16x8 pa0 = *(const s16x8*)&P_lds[li][jg * 8];
        const s16x8 pa1 = *(const s16x8*)&P_lds[li][32 + jg * 8];
#pragma unroll
        for (int ft = 0; ft < 4; ++ft) {
#pragma unroll
            for (int q = 0; q < 4; ++q) acc[ft][q] *= frv[q];
            acc[ft] = __builtin_amdgcn_mfma_f32_16x16x32_bf16(pa0, bv0[ft], acc[ft], 0, 0, 0);
            acc[ft] = __builtin_amdgcn_mfma_f32_16x16x32_bf16(pa1, bv1[ft], acc[ft], 0, 0, 0);
        }
        __syncthreads();
    }

    // ---- epilogue: 1/l broadcast, normalize, ELU, store
    if (li == 0) sF[orow] = 1.f / ll;
    __syncthreads();
    const f4 invv = *(const f4*)&sF[jg * 4];
#pragma unroll
    for (int ft = 0; ft < 4; ++ft) {
#pragma unroll
        for (int q = 0; q < 4; ++q) {
            float v = acc[ft][q] * invv[q];
            v = v > 0.f ? v : __builtin_amdgcn_exp2f(v * LOG2E) - 1.f;
            out[((size_t)b * N_ + i0 + jg * 4 + q) * F_ + fbase + ft * 16 + li] = v;
        }
    }
}

// ---------------------------------------------------------------------------
extern "C" void kernel_launch(void* const* d_in, const int* in_sizes, int n_in,
                              void* d_out, int out_size, void* d_ws, size_t ws_size,
                              hipStream_t stream) {
    const float* h = (const float*)d_in[0];
    const int* adj = (const int*)d_in[1];
    const float* W = (const float*)d_in[2];
    const float* a = (const float*)d_in[3];
    float* out = (float*)d_out;

    unsigned short* WhT = (unsigned short*)d_ws;                   // 8 MB
    float* wa = (float*)(WhT + (size_t)B_ * N_ * F_);              // 512 f32
    float* ei = wa + 512;                                          // 16384
    float* ej = ei + (size_t)B_ * N_;                              // 16384
    unsigned short* WTb = (unsigned short*)(ej + (size_t)B_ * N_); // 64K ushort
    unsigned long long* mask = (unsigned long long*)(WTb + 65536); // 2 MB

    k_pre<<<80, 256, 0, stream>>>(W, a, wa, WTb);
    k_big<<<6656, 256, 0, stream>>>(h, WTb, wa, adj, WhT, ei, ej, mask);
    k_attn<<<1024, 256, 0, stream>>>(WhT, ei, ej, mask, out);
}